// Round 10
// baseline (96.366 us; speedup 1.0000x reference)
//
#include <hip/hip_runtime.h>

typedef __attribute__((ext_vector_type(8))) __bf16 bf16x8;
typedef __attribute__((ext_vector_type(4))) __bf16 bf16x4;
typedef __attribute__((ext_vector_type(4))) float f32x4;

#define N_SAMP 256
#define DIM    2048
#define NCENT  32000
#define INV_T  14.285714285714285714f   // 1 / 0.07
#define NWG    250                       // one 256x128 tile per block
#define NSTEP  32                        // K / BK = 2048 / 64

// ---------------- kernel 1: row-normalize feats -> bf16; also zero d_acc ----------------
__global__ __launch_bounds__(256) void norm_kernel(const float* __restrict__ feats,
                                                   __bf16* __restrict__ fnorm,
                                                   float* __restrict__ d_acc) {
    int row = blockIdx.x;
    int tid = threadIdx.x;
    if (row < 16) d_acc[row * 256 + tid] = 0.f;   // zero 8 slots x 512 floats
    const float* src = feats + (size_t)row * DIM;
    float4 v0 = reinterpret_cast<const float4*>(src)[2 * tid];
    float4 v1 = reinterpret_cast<const float4*>(src)[2 * tid + 1];
    float ss = v0.x * v0.x + v0.y * v0.y + v0.z * v0.z + v0.w * v0.w
             + v1.x * v1.x + v1.y * v1.y + v1.z * v1.z + v1.w * v1.w;
    #pragma unroll
    for (int off = 1; off < 64; off <<= 1) ss += __shfl_xor(ss, off, 64);
    __shared__ float wsum[4];
    if ((tid & 63) == 0) wsum[tid >> 6] = ss;
    __syncthreads();
    float inv = 1.0f / sqrtf(wsum[0] + wsum[1] + wsum[2] + wsum[3]);
    bf16x8 o;
    o[0] = (__bf16)(v0.x * inv); o[1] = (__bf16)(v0.y * inv);
    o[2] = (__bf16)(v0.z * inv); o[3] = (__bf16)(v0.w * inv);
    o[4] = (__bf16)(v1.x * inv); o[5] = (__bf16)(v1.y * inv);
    o[6] = (__bf16)(v1.z * inv); o[7] = (__bf16)(v1.w * inv);
    *reinterpret_cast<bf16x8*>(fnorm + (size_t)row * DIM + tid * 8) = o;
}

// ------------- kernel 2: 256x128-tile, BK=64, 32 barrier-steps -------------
// 250 blocks x 512 threads (8 waves = 4m x 2n; wave tile 64x64, acc 4x4).
// A + B staged regs -> XOR-swizzled LDS (rows = 128 B; ^((row&7)<<4) covers
// all 32 banks over 8 rows). Depth-2 named register sets; raw s_barrier with
// lgkmcnt(0)-only drain (vmcnt stays counted across barriers).
__global__ __launch_bounds__(512, 2) void sims_kernel(
    const __bf16* __restrict__ fnorm, const float* __restrict__ centers,
    const int* __restrict__ labels, const int* __restrict__ camids,
    float* __restrict__ d_acc, float* __restrict__ d_own)
{
    __shared__ __align__(16) char sA[2][32768];  // 256 rows x 64 bf16 (128 B)
    __shared__ __align__(16) char sB[2][16384];  // 128 rows x 64 bf16 (128 B)

    const int tid  = threadIdx.x;
    const int wave = tid >> 6;
    const int lane = tid & 63;
    const int l15  = lane & 15;
    const int lhi  = lane >> 4;

    const int nb    = blockIdx.x;       // 0..249 center tile (128 centers)
    const int cbase = nb * 128;

    const int wr = (wave >> 1) * 64;    // wave rows within 256-row tile
    const int wc = (wave & 1) * 64;     // wave cols within 128-col tile

    f32x4 acc[4][4] = {};

    const float4* bsrc = reinterpret_cast<const float4*>(centers);
    const uint4*  asrc = reinterpret_cast<const uint4*>(fnorm);

    // A: thread -> row = tid>>1 (0..255), half = tid&1; 64 B (4 uint4) per thread
    // B: thread -> row = tid>>2 (0..127), quarter = tid&3; 64 B (4 float4) per thread
    const int arow = tid >> 1, ah = tid & 1;
    const int brow = tid >> 2, bq = tid & 3;

    auto issue = [&](int step, uint4 (&a)[4], float4 (&b)[4]) {
        #pragma unroll
        for (int q = 0; q < 4; ++q)
            a[q] = asrc[(size_t)arow * 256 + step * 8 + ah * 4 + q];
        #pragma unroll
        for (int q = 0; q < 4; ++q)
            b[q] = bsrc[(size_t)(cbase + brow) * 512 + step * 16 + bq * 4 + q];
    };
    auto wrbuf = [&](int buf, const uint4 (&a)[4], const float4 (&b)[4]) {
        #pragma unroll
        for (int q = 0; q < 4; ++q) {
            int lin = arow * 128 + ah * 64 + q * 16;
            int adr = lin ^ ((arow & 7) << 4);
            *reinterpret_cast<uint4*>(&sA[buf][adr]) = a[q];
        }
        #pragma unroll
        for (int q = 0; q < 4; ++q) {
            bf16x4 o;
            o[0] = (__bf16)b[q].x; o[1] = (__bf16)b[q].y;
            o[2] = (__bf16)b[q].z; o[3] = (__bf16)b[q].w;
            int lin = brow * 128 + bq * 32 + q * 8;
            int adr = lin ^ ((brow & 7) << 4);
            *reinterpret_cast<uint2*>(&sB[buf][adr]) = __builtin_bit_cast(uint2, o);
        }
    };
    auto compute_half = [&](int buf, int h) {
        bf16x8 af[4], bf[4];
        #pragma unroll
        for (int mi = 0; mi < 4; ++mi) {
            int row = wr + mi * 16 + l15;
            int adr = (row * 128 + h * 64 + lhi * 16) ^ ((row & 7) << 4);
            af[mi] = *reinterpret_cast<const bf16x8*>(&sA[buf][adr]);
        }
        #pragma unroll
        for (int ni = 0; ni < 4; ++ni) {
            int row = wc + ni * 16 + l15;
            int adr = (row * 128 + h * 64 + lhi * 16) ^ ((row & 7) << 4);
            bf[ni] = *reinterpret_cast<const bf16x8*>(&sB[buf][adr]);
        }
        #pragma unroll
        for (int mi = 0; mi < 4; ++mi)
            #pragma unroll
            for (int ni = 0; ni < 4; ++ni)
                acc[mi][ni] = __builtin_amdgcn_mfma_f32_16x16x32_bf16(
                    af[mi], bf[ni], acc[mi][ni], 0, 0, 0);
    };
    #define BAR() do { asm volatile("s_waitcnt lgkmcnt(0)" ::: "memory"); \
                       __builtin_amdgcn_s_barrier(); } while (0)

    uint4  aSA[4], aSB[4];
    float4 bSA[4], bSB[4];

    issue(0, aSA, bSA);
    issue(1, aSB, bSB);
    wrbuf(0, aSA, bSA);
    BAR();
    for (int t = 0; t < NSTEP; t += 2) {
        if (t + 2 < NSTEP) issue(t + 2, aSA, bSA);
        compute_half(0, 0);
        compute_half(0, 1);
        wrbuf(1, aSB, bSB);              // waits only set B; set A stays in flight
        BAR();
        if (t + 3 < NSTEP) issue(t + 3, aSB, bSB);
        compute_half(1, 0);
        compute_half(1, 1);
        if (t + 2 < NSTEP) {
            wrbuf(0, aSA, bSA);
            BAR();
        }
    }

    // ---- epilogue: exp + masks + per-sample partial denominators ----
    float* slot = d_acc + (nb & 7) * 512;
    #pragma unroll
    for (int mi = 0; mi < 4; ++mi) {
        #pragma unroll
        for (int r = 0; r < 4; ++r) {
            int i   = wr + mi * 16 + lhi * 4 + r;
            int lab = labels[i], cam = camids[i];
            int oidx = lab * 8 + cam;
            float pi = 0.f, pj = 0.f;
            #pragma unroll
            for (int ni = 0; ni < 4; ++ni) {
                int c = cbase + wc + ni * 16 + l15;
                float s = acc[mi][ni][r] * INV_T;
                float e = __expf(s);
                if ((l15 & 7) == cam) pi += e;          // c % 8 == cam
                bool ol = ((c >> 3) == lab);
                bool hard = (!ol) && (c < ((c < lab * 8) ? 50 : 58));
                if (ol || hard) pj += e;
                if (c == oidx) d_own[i] = s;
            }
            #pragma unroll
            for (int off = 1; off < 16; off <<= 1) {
                pi += __shfl_xor(pi, off, 64);
                pj += __shfl_xor(pj, off, 64);
            }
            if (l15 == 0) {
                atomicAdd(&slot[i], pi);
                atomicAdd(&slot[N_SAMP + i], pj);
            }
        }
    }
}

// ---------------- kernel 3: finalize (segment means + output) ----------------
__global__ __launch_bounds__(256) void finalize_kernel(
    const float* __restrict__ d_acc, const float* __restrict__ d_own,
    const int* __restrict__ labels, const int* __restrict__ camids,
    float* __restrict__ out, int out_size)
{
    __shared__ int s_lab[N_SAMP], s_cam[N_SAMP];
    __shared__ float wsum[8];
    int tid = threadIdx.x;
    s_lab[tid] = labels[tid];
    s_cam[tid] = camids[tid];
    __syncthreads();
    int myl = s_lab[tid], myc = s_cam[tid];
    int nl = 0, nc = 0;
    for (int j = 0; j < N_SAMP; ++j) {
        nl += (s_lab[j] == myl);
        nc += (s_cam[j] == myc);
    }
    float di = 0.f, dj = 0.f;
    #pragma unroll
    for (int s = 0; s < 8; ++s) {
        di += d_acc[s * 512 + tid];
        dj += d_acc[s * 512 + 256 + tid];
    }
    float own = d_own[tid];
    float li = own - logf(di);
    float lj = own - logf(dj);
    float a = li / (float)nc;   // sum_i loss_i / n_cam == sum over cams of per-cam mean
    float b = lj / (float)nl;
    #pragma unroll
    for (int off = 1; off < 64; off <<= 1) {
        a += __shfl_xor(a, off, 64);
        b += __shfl_xor(b, off, 64);
    }
    if ((tid & 63) == 0) { wsum[tid >> 6] = a; wsum[4 + (tid >> 6)] = b; }
    __syncthreads();
    if (tid == 0) {
        float sa = wsum[0] + wsum[1] + wsum[2] + wsum[3];
        float sb = wsum[4] + wsum[5] + wsum[6] + wsum[7];
        out[0] = -sa;
        if (out_size > 1) out[1] = -0.5f * sb;   // LAMDA = 0.5
    }
}

extern "C" void kernel_launch(void* const* d_in, const int* in_sizes, int n_in,
                              void* d_out, int out_size, void* d_ws, size_t ws_size,
                              hipStream_t stream) {
    const float* feats   = (const float*)d_in[0];
    const float* centers = (const float*)d_in[1];
    const int*   labels  = (const int*)d_in[2];
    const int*   camids  = (const int*)d_in[3];
    float* out = (float*)d_out;

    __bf16* fnorm = (__bf16*)d_ws;
    float* d_acc  = (float*)((char*)d_ws + (size_t)N_SAMP * DIM * sizeof(__bf16));
    float* d_own  = d_acc + 8 * 2 * N_SAMP;

    norm_kernel<<<N_SAMP, 256, 0, stream>>>(feats, fnorm, d_acc);
    sims_kernel<<<NWG, 512, 0, stream>>>(fnorm, centers, labels, camids, d_acc, d_own);
    finalize_kernel<<<1, 256, 0, stream>>>(d_acc, d_own, labels, camids, out, out_size);
}